// Round 4
// baseline (1572.891 us; speedup 1.0000x reference)
//
#include <hip/hip_runtime.h>
#include <stdint.h>

typedef unsigned long long u64;
typedef unsigned int u32;

#define BIMG 8
#define NPROP 1000
#define DDIM 512
#define CCLS 1203
#define MAXOUT 300
#define CSLOT 4096      // per-image candidate slots: 1000 rows * 4, padded to pow2
#define TRIW 8665       // sum_i (16 - ((i+1)>>6)) upper-triangle u64 words

__device__ __forceinline__ u32 flipf(float f) {
  u32 u = __float_as_uint(f);
  return (u & 0x80000000u) ? ~u : (u | 0x80000000u);
}
__device__ __forceinline__ float unflipf(u32 x) {
  u32 u = (x & 0x80000000u) ? (x ^ 0x80000000u) : ~x;
  return __uint_as_float(u);
}
__device__ __forceinline__ void push3(float v, float& a0, float& a1, float& a2) {
  if (v > a0) { a2 = a1; a1 = a0; a0 = v; }
  else if (v > a1) { a2 = a1; a1 = v; }
  else if (v > a2) { a2 = v; }
}

// ---------------- stage 1: normalize + logits + softmax + top3-clip + per-row best-4 emit
__global__ __launch_bounds__(256) void score_kernel(
    const float* __restrict__ pe, const float* __restrict__ obj,
    const float* __restrict__ ce, u64* __restrict__ cand)
{
  __shared__ float pe_s[8][DDIM];      // 16 KB
  __shared__ float red[4][8];
  __shared__ float trip[4][8][3];
  __shared__ u64 rowc[8][16];          // 1 KB
  __shared__ u32 rcnt[8];

  const int tid = threadIdx.x;
  const int lane = tid & 63, wv = tid >> 6;
  const int blk = blockIdx.x;
  const int b = blk / 125;
  const int n0 = (blk % 125) * 8;

  {
    const float4* src = (const float4*)(pe + (size_t)(b * NPROP + n0) * DDIM);
    float4* dst = (float4*)&pe_s[0][0];
    for (int i = tid; i < 1024; i += 256) dst[i] = src[i];
  }
  if (tid < 8) rcnt[tid] = 0u;
  __syncthreads();

  // row norms
  float nrm[8];
  #pragma unroll
  for (int r = 0; r < 8; r++) {
    float x0 = pe_s[r][tid], x1 = pe_s[r][tid + 256];
    float s = x0 * x0 + x1 * x1;
    #pragma unroll
    for (int off = 32; off; off >>= 1) s += __shfl_xor(s, off);
    if (lane == 0) red[wv][r] = s;
  }
  __syncthreads();
  #pragma unroll
  for (int r = 0; r < 8; r++)
    nrm[r] = sqrtf(((red[0][r] + red[1][r]) + red[2][r]) + red[3][r]);
  __syncthreads();
  #pragma unroll
  for (int r = 0; r < 8; r++) {
    pe_s[r][tid]       = __fdiv_rn(pe_s[r][tid], nrm[r]);
    pe_s[r][tid + 256] = __fdiv_rn(pe_s[r][tid + 256], nrm[r]);
  }
  __syncthreads();

  // dots: thread covers classes tid + 256k
  const int c4 = 1024 + tid;
  const bool v4 = (c4 < CCLS);
  const float4* ceb = (const float4*)ce;
  const float4* pc0 = ceb + (size_t)(tid)       * 128;
  const float4* pc1 = ceb + (size_t)(tid + 256) * 128;
  const float4* pc2 = ceb + (size_t)(tid + 512) * 128;
  const float4* pc3 = ceb + (size_t)(tid + 768) * 128;
  const float4* pc4 = ceb + (size_t)(v4 ? c4 : (CCLS - 1)) * 128;

  float acc[5][8];
  #pragma unroll
  for (int k = 0; k < 5; k++)
    #pragma unroll
    for (int r = 0; r < 8; r++) acc[k][r] = 0.f;

  const float4* ps4 = (const float4*)&pe_s[0][0];
  for (int d4 = 0; d4 < 128; d4++) {
    float4 bv0 = pc0[d4], bv1 = pc1[d4], bv2 = pc2[d4], bv3 = pc3[d4], bv4 = pc4[d4];
    #pragma unroll
    for (int r = 0; r < 8; r++) {
      float4 a = ps4[r * 128 + d4];
      acc[0][r] = fmaf(a.x, bv0.x, acc[0][r]); acc[0][r] = fmaf(a.y, bv0.y, acc[0][r]);
      acc[0][r] = fmaf(a.z, bv0.z, acc[0][r]); acc[0][r] = fmaf(a.w, bv0.w, acc[0][r]);
      acc[1][r] = fmaf(a.x, bv1.x, acc[1][r]); acc[1][r] = fmaf(a.y, bv1.y, acc[1][r]);
      acc[1][r] = fmaf(a.z, bv1.z, acc[1][r]); acc[1][r] = fmaf(a.w, bv1.w, acc[1][r]);
      acc[2][r] = fmaf(a.x, bv2.x, acc[2][r]); acc[2][r] = fmaf(a.y, bv2.y, acc[2][r]);
      acc[2][r] = fmaf(a.z, bv2.z, acc[2][r]); acc[2][r] = fmaf(a.w, bv2.w, acc[2][r]);
      acc[3][r] = fmaf(a.x, bv3.x, acc[3][r]); acc[3][r] = fmaf(a.y, bv3.y, acc[3][r]);
      acc[3][r] = fmaf(a.z, bv3.z, acc[3][r]); acc[3][r] = fmaf(a.w, bv3.w, acc[3][r]);
      acc[4][r] = fmaf(a.x, bv4.x, acc[4][r]); acc[4][r] = fmaf(a.y, bv4.y, acc[4][r]);
      acc[4][r] = fmaf(a.z, bv4.z, acc[4][r]); acc[4][r] = fmaf(a.w, bv4.w, acc[4][r]);
    }
  }

  #pragma unroll
  for (int k = 0; k < 5; k++)
    #pragma unroll
    for (int r = 0; r < 8; r++) acc[k][r] = __fdiv_rn(acc[k][r], 0.01f);
  if (!v4) {
    #pragma unroll
    for (int r = 0; r < 8; r++) acc[4][r] = -INFINITY;
  }

  // per-row top-3 of logits
  float t0[8], t1[8], t2[8];
  #pragma unroll
  for (int r = 0; r < 8; r++) {
    t0[r] = t1[r] = t2[r] = -INFINITY;
    push3(acc[0][r], t0[r], t1[r], t2[r]);
    push3(acc[1][r], t0[r], t1[r], t2[r]);
    push3(acc[2][r], t0[r], t1[r], t2[r]);
    push3(acc[3][r], t0[r], t1[r], t2[r]);
    push3(acc[4][r], t0[r], t1[r], t2[r]);
  }
  #pragma unroll
  for (int off = 32; off; off >>= 1) {
    #pragma unroll
    for (int r = 0; r < 8; r++) {
      float u0 = __shfl_xor(t0[r], off);
      float u1 = __shfl_xor(t1[r], off);
      float u2 = __shfl_xor(t2[r], off);
      push3(u0, t0[r], t1[r], t2[r]);
      push3(u1, t0[r], t1[r], t2[r]);
      push3(u2, t0[r], t1[r], t2[r]);
    }
  }
  if (lane == 0) {
    #pragma unroll
    for (int r = 0; r < 8; r++) {
      trip[wv][r][0] = t0[r]; trip[wv][r][1] = t1[r]; trip[wv][r][2] = t2[r];
    }
  }
  __syncthreads();
  float m[8], s3[8];
  #pragma unroll
  for (int r = 0; r < 8; r++) {
    float a0 = -INFINITY, a1 = -INFINITY, a2 = -INFINITY;
    #pragma unroll
    for (int w = 0; w < 4; w++) {
      push3(trip[w][r][0], a0, a1, a2);
      push3(trip[w][r][1], a0, a1, a2);
      push3(trip[w][r][2], a0, a1, a2);
    }
    m[r] = a0; s3[r] = a2;
  }

  // softmax denominator
  float sm[8];
  #pragma unroll
  for (int r = 0; r < 8; r++) {
    float ls = expf(acc[0][r] - m[r]);
    ls += expf(acc[1][r] - m[r]);
    ls += expf(acc[2][r] - m[r]);
    ls += expf(acc[3][r] - m[r]);
    ls += expf(acc[4][r] - m[r]);
    #pragma unroll
    for (int off = 32; off; off >>= 1) ls += __shfl_xor(ls, off);
    if (lane == 0) red[wv][r] = ls;
  }
  __syncthreads();
  #pragma unroll
  for (int r = 0; r < 8; r++)
    sm[r] = ((red[0][r] + red[1][r]) + red[2][r]) + red[3][r];

  float v3[8], objv[8];
  #pragma unroll
  for (int r = 0; r < 8; r++) {
    v3[r] = __fdiv_rn(expf(s3[r] - m[r]), sm[r]);
    objv[r] = obj[b * NPROP + n0 + r];
  }

  // emit: p >= v3 && p > 0 && score > 0.01 -> collect in LDS
  #pragma unroll
  for (int k = 0; k < 5; k++) {
    if (k == 4 && !v4) continue;
    const int c = tid + (k << 8);
    #pragma unroll
    for (int r = 0; r < 8; r++) {
      float e = expf(acc[k][r] - m[r]);
      float p = __fdiv_rn(e, sm[r]);
      if (p >= v3[r] && p > 0.f) {
        float sc = __fadd_rn(__fmul_rn(p, 0.65f), __fmul_rn(objv[r], 0.35f));
        if (sc > 0.01f) {
          u32 flat = (u32)(n0 + r) * (u32)CCLS + (u32)c;
          u64 key = (((u64)flipf(sc)) << 32) | (u32)(~flat);
          u32 slot = atomicAdd(&rcnt[r], 1u);
          if (slot < 16u) rowc[r][slot] = key;
        }
      }
    }
  }
  __syncthreads();
  // per-row sort (desc key = score desc, flat asc) and write best-4
  if (tid < 8) {
    int n = (int)rcnt[tid]; if (n > 16) n = 16;
    for (int a2 = 1; a2 < n; a2++) {
      u64 kx = rowc[tid][a2]; int bp = a2 - 1;
      while (bp >= 0 && rowc[tid][bp] < kx) { rowc[tid][bp + 1] = rowc[tid][bp]; bp--; }
      rowc[tid][bp + 1] = kx;
    }
    int mth = n < 4 ? n : 4;
    u64* dst = cand + (size_t)b * CSLOT + (size_t)(n0 + tid) * 4;
    for (int s2 = 0; s2 < mth; s2++) dst[s2] = rowc[tid][s2];
  }
}

// ---------------- stage 2: per-image in-place bitonic sort of 4096 keys (desc)
__global__ __launch_bounds__(1024) void sort_kernel(u64* __restrict__ cand)
{
  __shared__ u64 s[CSLOT];   // 32 KB
  const int tid = threadIdx.x;
  u64* cb = cand + (size_t)blockIdx.x * CSLOT;
  for (int i = tid; i < CSLOT; i += 1024) s[i] = cb[i];
  __syncthreads();
  for (int k = 2; k <= CSLOT; k <<= 1) {
    for (int j = k >> 1; j > 0; j >>= 1) {
      for (int i = tid; i < CSLOT; i += 1024) {
        int ixj = i ^ j;
        if (ixj > i) {
          u64 a = s[i], c = s[ixj];
          if (((i & k) == 0) ? (a < c) : (a > c)) { s[i] = c; s[ixj] = a; }
        }
      }
      __syncthreads();
    }
  }
  for (int i = tid; i < CSLOT; i += 1024) cb[i] = s[i];
}

// ---------------- stage 3: fused decode + triangle IoU + serial greedy NMS + f32 output
__global__ __launch_bounds__(1024) void nms_fused(
    const u64* __restrict__ cand, const float* __restrict__ boxes,
    const int* __restrict__ image_ids, float* __restrict__ out)
{
  __shared__ u64 supw[TRIW];       // 69,320 B (upper-triangle, ragged rows)
  __shared__ float4 bx[NPROP];     // 16,000 B
  __shared__ float ar[NPROP];
  __shared__ float scs[NPROP];
  __shared__ int lbs[NPROP];
  __shared__ u64 kw[16];

  const int tid = threadIdx.x;
  const int b = blockIdx.x;

  // phase A: decode sorted keys, gather boxes
  for (int i = tid; i < NPROP; i += 1024) {
    u64 key = cand[(size_t)b * CSLOT + i];
    float sc = -1.0f; int pid = 0, lab = -1;
    if (key != 0ull) {
      sc = unflipf((u32)(key >> 32));
      u32 flat = ~(u32)key;
      pid = (int)(flat / (u32)CCLS);
      lab = (int)(flat % (u32)CCLS);
    }
    float4 v = ((const float4*)boxes)[b * NPROP + pid];
    bx[i] = v;
    ar[i] = __fmul_rn(fmaxf(__fsub_rn(v.z, v.x), 0.f),
                      fmaxf(__fsub_rn(v.w, v.y), 0.f));
    scs[i] = sc;
    lbs[i] = lab;
  }
  __syncthreads();

  // phase B: upper-triangle suppression bits (j > i only)
  for (int i = tid; i < NPROP; i += 1024) {
    float4 bi = bx[i]; float ai = ar[i]; int li = lbs[i];
    int g = i >> 6, t = i - (g << 6);
    int rb = 16 * i - (32 * g * (g - 1) + g * (t + 1));   // base(i)
    int w0 = (i + 1) >> 6;
    for (int w = w0; w < 16; w++) {
      u64 bits = 0;
      int jb = w << 6;
      int ts = (w == g) ? (t + 1) : 0;
      int te = NPROP - jb; if (te > 64) te = 64;
      for (int tt = ts; tt < te; tt++) {
        int j = jb + tt;
        if (lbs[j] != li) continue;
        float4 bj = bx[j];
        float iw = fmaxf(__fsub_rn(fminf(bi.z, bj.z), fmaxf(bi.x, bj.x)), 0.f);
        float ih = fmaxf(__fsub_rn(fminf(bi.w, bj.w), fmaxf(bi.y, bj.y)), 0.f);
        float inter = __fmul_rn(iw, ih);
        float uni = __fsub_rn(__fadd_rn(ai, ar[j]), inter);
        if (__fdiv_rn(inter, fmaxf(uni, 1e-6f)) > 0.5f) bits |= (1ull << tt);
      }
      supw[rb + w - w0] = bits;
    }
  }
  __syncthreads();

  // phase C: serial greedy NMS (single thread; mirrors the fori_loop exactly)
  if (tid == 0) {
    #pragma unroll
    for (int w = 0; w < 16; w++) kw[w] = 0;
    for (int i = 0; i < NPROP; i++)
      if (scs[i] > 0.01f) kw[i >> 6] |= (1ull << (i & 63));
    int base = 0;
    for (int i = 0; i < NPROP; i++) {
      int w0 = (i + 1) >> 6;
      if ((kw[i >> 6] >> (i & 63)) & 1ull) {
        for (int w = w0; w < 16; w++) kw[w] &= ~supw[base + w - w0];
      }
      base += 16 - w0;
    }
  }
  __syncthreads();

  // phase D1: parallel init of this image's entire output slice (f32)
  for (int j = tid; j < MAXOUT * 5; j += 1024)
    out[(size_t)b * MAXOUT * 5 + j] = 0.f;
  for (int j = tid; j < MAXOUT; j += 1024) {
    out[BIMG * MAXOUT * 5 + b * MAXOUT + j] = -1.f;
    out[BIMG * MAXOUT * 6 + b * MAXOUT + j] = -1.f;
  }
  __syncthreads();

  // phase D2: serial ordered write of first 300 kept rows (f32)
  if (tid == 0) {
    float imgv = (float)image_ids[b];
    int rank = 0;
    for (int i = 0; i < NPROP && rank < MAXOUT; i++) {
      if ((kw[i >> 6] >> (i & 63)) & 1ull) {
        float4 bv = bx[i];
        size_t ro = (size_t)(b * MAXOUT + rank) * 5;
        out[ro + 0] = bv.x;
        out[ro + 1] = bv.y;
        out[ro + 2] = bv.z;
        out[ro + 3] = bv.w;
        out[ro + 4] = scs[i];
        out[BIMG * MAXOUT * 5 + b * MAXOUT + rank] = (float)lbs[i];
        out[BIMG * MAXOUT * 6 + b * MAXOUT + rank] = imgv;
        rank++;
      }
    }
  }
}

extern "C" void kernel_launch(void* const* d_in, const int* in_sizes, int n_in,
                              void* d_out, int out_size, void* d_ws, size_t ws_size,
                              hipStream_t stream) {
  (void)in_sizes; (void)n_in; (void)out_size; (void)ws_size;
  const float* pe = (const float*)d_in[0];
  const float* obj = (const float*)d_in[1];
  const float* boxes = (const float*)d_in[2];
  const float* ce = (const float*)d_in[3];
  const int* image_ids = (const int*)d_in[4];
  float* out = (float*)d_out;

  u64* cand = (u64*)d_ws;   // 8 * 4096 * 8 B = 256 KB total scratch

  hipMemsetAsync(cand, 0, (size_t)BIMG * CSLOT * sizeof(u64), stream);
  score_kernel<<<dim3(1000), dim3(256), 0, stream>>>(pe, obj, ce, cand);
  sort_kernel<<<dim3(BIMG), dim3(1024), 0, stream>>>(cand);
  nms_fused<<<dim3(BIMG), dim3(1024), 0, stream>>>(cand, boxes, image_ids, out);
}

// Round 5
// 968.475 us; speedup vs baseline: 1.6241x; 1.6241x over previous
//
#include <hip/hip_runtime.h>
#include <stdint.h>

typedef unsigned long long u64;
typedef unsigned int u32;

#define BIMG 8
#define NPROP 1000
#define DDIM 512
#define CCLS 1203
#define MAXOUT 300
#define CSLOT 4096      // per-image candidate slots: 1000 rows * 4, padded to pow2
#define TRIW 8665       // sum_i (16 - ((i+1)>>6)) upper-triangle u64 words

__device__ __forceinline__ u32 flipf(float f) {
  u32 u = __float_as_uint(f);
  return (u & 0x80000000u) ? ~u : (u | 0x80000000u);
}
__device__ __forceinline__ float unflipf(u32 x) {
  u32 u = (x & 0x80000000u) ? (x ^ 0x80000000u) : ~x;
  return __uint_as_float(u);
}
__device__ __forceinline__ void push3(float v, float& a0, float& a1, float& a2) {
  if (v > a0) { a2 = a1; a1 = a0; a0 = v; }
  else if (v > a1) { a2 = a1; a1 = v; }
  else if (v > a2) { a2 = v; }
}

// ---------------- stage 1: normalize + logits + softmax + top3-clip + per-row best-4 emit
__global__ __launch_bounds__(256) void score_kernel(
    const float* __restrict__ pe, const float* __restrict__ obj,
    const float* __restrict__ ce, u64* __restrict__ cand)
{
  __shared__ float pe_s[8][DDIM];      // 16 KB
  __shared__ float red[4][8];
  __shared__ float trip[4][8][3];
  __shared__ u64 rowc[8][16];          // 1 KB
  __shared__ u32 rcnt[8];

  const int tid = threadIdx.x;
  const int lane = tid & 63, wv = tid >> 6;
  const int blk = blockIdx.x;
  const int b = blk / 125;
  const int n0 = (blk % 125) * 8;

  {
    const float4* src = (const float4*)(pe + (size_t)(b * NPROP + n0) * DDIM);
    float4* dst = (float4*)&pe_s[0][0];
    for (int i = tid; i < 1024; i += 256) dst[i] = src[i];
  }
  if (tid < 8) rcnt[tid] = 0u;
  __syncthreads();

  // row norms
  float nrm[8];
  #pragma unroll
  for (int r = 0; r < 8; r++) {
    float x0 = pe_s[r][tid], x1 = pe_s[r][tid + 256];
    float s = x0 * x0 + x1 * x1;
    #pragma unroll
    for (int off = 32; off; off >>= 1) s += __shfl_xor(s, off);
    if (lane == 0) red[wv][r] = s;
  }
  __syncthreads();
  #pragma unroll
  for (int r = 0; r < 8; r++)
    nrm[r] = sqrtf(((red[0][r] + red[1][r]) + red[2][r]) + red[3][r]);
  __syncthreads();
  #pragma unroll
  for (int r = 0; r < 8; r++) {
    pe_s[r][tid]       = __fdiv_rn(pe_s[r][tid], nrm[r]);
    pe_s[r][tid + 256] = __fdiv_rn(pe_s[r][tid + 256], nrm[r]);
  }
  __syncthreads();

  // dots: thread covers classes tid + 256k
  const int c4 = 1024 + tid;
  const bool v4 = (c4 < CCLS);
  const float4* ceb = (const float4*)ce;
  const float4* pc0 = ceb + (size_t)(tid)       * 128;
  const float4* pc1 = ceb + (size_t)(tid + 256) * 128;
  const float4* pc2 = ceb + (size_t)(tid + 512) * 128;
  const float4* pc3 = ceb + (size_t)(tid + 768) * 128;
  const float4* pc4 = ceb + (size_t)(v4 ? c4 : (CCLS - 1)) * 128;

  float acc[5][8];
  #pragma unroll
  for (int k = 0; k < 5; k++)
    #pragma unroll
    for (int r = 0; r < 8; r++) acc[k][r] = 0.f;

  const float4* ps4 = (const float4*)&pe_s[0][0];
  for (int d4 = 0; d4 < 128; d4++) {
    float4 bv0 = pc0[d4], bv1 = pc1[d4], bv2 = pc2[d4], bv3 = pc3[d4], bv4 = pc4[d4];
    #pragma unroll
    for (int r = 0; r < 8; r++) {
      float4 a = ps4[r * 128 + d4];
      acc[0][r] = fmaf(a.x, bv0.x, acc[0][r]); acc[0][r] = fmaf(a.y, bv0.y, acc[0][r]);
      acc[0][r] = fmaf(a.z, bv0.z, acc[0][r]); acc[0][r] = fmaf(a.w, bv0.w, acc[0][r]);
      acc[1][r] = fmaf(a.x, bv1.x, acc[1][r]); acc[1][r] = fmaf(a.y, bv1.y, acc[1][r]);
      acc[1][r] = fmaf(a.z, bv1.z, acc[1][r]); acc[1][r] = fmaf(a.w, bv1.w, acc[1][r]);
      acc[2][r] = fmaf(a.x, bv2.x, acc[2][r]); acc[2][r] = fmaf(a.y, bv2.y, acc[2][r]);
      acc[2][r] = fmaf(a.z, bv2.z, acc[2][r]); acc[2][r] = fmaf(a.w, bv2.w, acc[2][r]);
      acc[3][r] = fmaf(a.x, bv3.x, acc[3][r]); acc[3][r] = fmaf(a.y, bv3.y, acc[3][r]);
      acc[3][r] = fmaf(a.z, bv3.z, acc[3][r]); acc[3][r] = fmaf(a.w, bv3.w, acc[3][r]);
      acc[4][r] = fmaf(a.x, bv4.x, acc[4][r]); acc[4][r] = fmaf(a.y, bv4.y, acc[4][r]);
      acc[4][r] = fmaf(a.z, bv4.z, acc[4][r]); acc[4][r] = fmaf(a.w, bv4.w, acc[4][r]);
    }
  }

  #pragma unroll
  for (int k = 0; k < 5; k++)
    #pragma unroll
    for (int r = 0; r < 8; r++) acc[k][r] = __fdiv_rn(acc[k][r], 0.01f);
  if (!v4) {
    #pragma unroll
    for (int r = 0; r < 8; r++) acc[4][r] = -INFINITY;
  }

  // per-row top-3 of logits
  float t0[8], t1[8], t2[8];
  #pragma unroll
  for (int r = 0; r < 8; r++) {
    t0[r] = t1[r] = t2[r] = -INFINITY;
    push3(acc[0][r], t0[r], t1[r], t2[r]);
    push3(acc[1][r], t0[r], t1[r], t2[r]);
    push3(acc[2][r], t0[r], t1[r], t2[r]);
    push3(acc[3][r], t0[r], t1[r], t2[r]);
    push3(acc[4][r], t0[r], t1[r], t2[r]);
  }
  #pragma unroll
  for (int off = 32; off; off >>= 1) {
    #pragma unroll
    for (int r = 0; r < 8; r++) {
      float u0 = __shfl_xor(t0[r], off);
      float u1 = __shfl_xor(t1[r], off);
      float u2 = __shfl_xor(t2[r], off);
      push3(u0, t0[r], t1[r], t2[r]);
      push3(u1, t0[r], t1[r], t2[r]);
      push3(u2, t0[r], t1[r], t2[r]);
    }
  }
  if (lane == 0) {
    #pragma unroll
    for (int r = 0; r < 8; r++) {
      trip[wv][r][0] = t0[r]; trip[wv][r][1] = t1[r]; trip[wv][r][2] = t2[r];
    }
  }
  __syncthreads();
  float m[8], s3[8];
  #pragma unroll
  for (int r = 0; r < 8; r++) {
    float a0 = -INFINITY, a1 = -INFINITY, a2 = -INFINITY;
    #pragma unroll
    for (int w = 0; w < 4; w++) {
      push3(trip[w][r][0], a0, a1, a2);
      push3(trip[w][r][1], a0, a1, a2);
      push3(trip[w][r][2], a0, a1, a2);
    }
    m[r] = a0; s3[r] = a2;
  }

  // softmax denominator
  float sm[8];
  #pragma unroll
  for (int r = 0; r < 8; r++) {
    float ls = expf(acc[0][r] - m[r]);
    ls += expf(acc[1][r] - m[r]);
    ls += expf(acc[2][r] - m[r]);
    ls += expf(acc[3][r] - m[r]);
    ls += expf(acc[4][r] - m[r]);
    #pragma unroll
    for (int off = 32; off; off >>= 1) ls += __shfl_xor(ls, off);
    if (lane == 0) red[wv][r] = ls;
  }
  __syncthreads();
  #pragma unroll
  for (int r = 0; r < 8; r++)
    sm[r] = ((red[0][r] + red[1][r]) + red[2][r]) + red[3][r];

  float v3[8], objv[8];
  #pragma unroll
  for (int r = 0; r < 8; r++) {
    v3[r] = __fdiv_rn(expf(s3[r] - m[r]), sm[r]);
    objv[r] = obj[b * NPROP + n0 + r];
  }

  // emit: p >= v3 && p > 0 && score > 0.01 -> collect in LDS
  #pragma unroll
  for (int k = 0; k < 5; k++) {
    if (k == 4 && !v4) continue;
    const int c = tid + (k << 8);
    #pragma unroll
    for (int r = 0; r < 8; r++) {
      float e = expf(acc[k][r] - m[r]);
      float p = __fdiv_rn(e, sm[r]);
      if (p >= v3[r] && p > 0.f) {
        float sc = __fadd_rn(__fmul_rn(p, 0.65f), __fmul_rn(objv[r], 0.35f));
        if (sc > 0.01f) {
          u32 flat = (u32)(n0 + r) * (u32)CCLS + (u32)c;
          u64 key = (((u64)flipf(sc)) << 32) | (u32)(~flat);
          u32 slot = atomicAdd(&rcnt[r], 1u);
          if (slot < 16u) rowc[r][slot] = key;
        }
      }
    }
  }
  __syncthreads();
  // per-row sort (desc key = score desc, flat asc) and write best-4
  if (tid < 8) {
    int n = (int)rcnt[tid]; if (n > 16) n = 16;
    for (int a2 = 1; a2 < n; a2++) {
      u64 kx = rowc[tid][a2]; int bp = a2 - 1;
      while (bp >= 0 && rowc[tid][bp] < kx) { rowc[tid][bp + 1] = rowc[tid][bp]; bp--; }
      rowc[tid][bp + 1] = kx;
    }
    int mth = n < 4 ? n : 4;
    u64* dst = cand + (size_t)b * CSLOT + (size_t)(n0 + tid) * 4;
    for (int s2 = 0; s2 < mth; s2++) dst[s2] = rowc[tid][s2];
  }
}

// ---------------- stage 2: per-image in-place bitonic sort of 4096 keys (desc)
__global__ __launch_bounds__(1024) void sort_kernel(u64* __restrict__ cand)
{
  __shared__ u64 s[CSLOT];   // 32 KB
  const int tid = threadIdx.x;
  u64* cb = cand + (size_t)blockIdx.x * CSLOT;
  for (int i = tid; i < CSLOT; i += 1024) s[i] = cb[i];
  __syncthreads();
  for (int k = 2; k <= CSLOT; k <<= 1) {
    for (int j = k >> 1; j > 0; j >>= 1) {
      for (int i = tid; i < CSLOT; i += 1024) {
        int ixj = i ^ j;
        if (ixj > i) {
          u64 a = s[i], c = s[ixj];
          if (((i & k) == 0) ? (a < c) : (a > c)) { s[i] = c; s[ixj] = a; }
        }
      }
      __syncthreads();
    }
  }
  for (int i = tid; i < CSLOT; i += 1024) cb[i] = s[i];
}

// ---------------- stage 3: fused decode + triangle IoU + wave-parallel greedy NMS + f32 output
__global__ __launch_bounds__(1024) void nms_fused(
    const u64* __restrict__ cand, const float* __restrict__ boxes,
    const int* __restrict__ image_ids, float* __restrict__ out)
{
  __shared__ u64 supw[TRIW];       // 69,320 B (upper-triangle, ragged rows)
  __shared__ float4 bx[NPROP];     // 16,000 B
  __shared__ float ar[NPROP];
  __shared__ float scs[NPROP];
  __shared__ int lbs[NPROP];

  const int tid = threadIdx.x;
  const int b = blockIdx.x;

  // phase A: decode sorted keys, gather boxes
  for (int i = tid; i < NPROP; i += 1024) {
    u64 key = cand[(size_t)b * CSLOT + i];
    float sc = -1.0f; int pid = 0, lab = -1;
    if (key != 0ull) {
      sc = unflipf((u32)(key >> 32));
      u32 flat = ~(u32)key;
      pid = (int)(flat / (u32)CCLS);
      lab = (int)(flat % (u32)CCLS);
    }
    float4 v = ((const float4*)boxes)[b * NPROP + pid];
    bx[i] = v;
    ar[i] = __fmul_rn(fmaxf(__fsub_rn(v.z, v.x), 0.f),
                      fmaxf(__fsub_rn(v.w, v.y), 0.f));
    scs[i] = sc;
    lbs[i] = lab;
  }
  __syncthreads();

  // phase B: upper-triangle suppression bits (j > i only)
  for (int i = tid; i < NPROP; i += 1024) {
    float4 bi = bx[i]; float ai = ar[i]; int li = lbs[i];
    int g = i >> 6, t = i - (g << 6);
    int rb = 16 * i - (32 * g * (g - 1) + g * (t + 1));   // base(i)
    int w0 = (i + 1) >> 6;
    for (int w = w0; w < 16; w++) {
      u64 bits = 0;
      int jb = w << 6;
      int ts = (w == g) ? (t + 1) : 0;
      int te = NPROP - jb; if (te > 64) te = 64;
      for (int tt = ts; tt < te; tt++) {
        int j = jb + tt;
        if (lbs[j] != li) continue;
        float4 bj = bx[j];
        float iw = fmaxf(__fsub_rn(fminf(bi.z, bj.z), fmaxf(bi.x, bj.x)), 0.f);
        float ih = fmaxf(__fsub_rn(fminf(bi.w, bj.w), fmaxf(bi.y, bj.y)), 0.f);
        float inter = __fmul_rn(iw, ih);
        if (inter <= 0.f) continue;      // IoU would be 0 -> never > 0.5
        float uni = __fsub_rn(__fadd_rn(ai, ar[j]), inter);
        if (__fdiv_rn(inter, fmaxf(uni, 1e-6f)) > 0.5f) bits |= (1ull << tt);
      }
      supw[rb + w - w0] = bits;
    }
  }
  __syncthreads();

  // phase D1: parallel init of this image's entire output slice (f32)
  for (int j = tid; j < MAXOUT * 5; j += 1024)
    out[(size_t)b * MAXOUT * 5 + j] = 0.f;
  for (int j = tid; j < MAXOUT; j += 1024) {
    out[BIMG * MAXOUT * 5 + b * MAXOUT + j] = -1.f;
    out[BIMG * MAXOUT * 6 + b * MAXOUT + j] = -1.f;
  }
  __syncthreads();

  if (tid >= 64) return;     // wave 0 finishes alone (no more barriers below)
  const int lane = tid, myw = lane & 15;

  // phase C: greedy NMS, keep bits distributed over lanes 0-15, 4-deep row prefetch
  u64 keep = 0;
  if (lane < 16) {
    #pragma unroll 4
    for (int t = 0; t < 64; t++) {
      int i = (lane << 6) + t;
      if (i < NPROP && scs[i] > 0.01f) keep |= (1ull << t);
    }
  }

  auto LDROW = [&](int i) -> u64 {   // lane myw's word of row i's suppression bits
    if (i >= NPROP || lane >= 16) return 0ull;
    int g = i >> 6, t = i & 63;
    int w0 = (i + 1) >> 6;
    if (myw < w0) return 0ull;
    int rb = 16 * i - (32 * g * (g - 1) + g * (t + 1));
    return supw[rb + myw - w0];
  };

  u64 p0 = LDROW(0), p1 = LDROW(1), p2 = LDROW(2), p3 = LDROW(3);
  for (int i = 0; i < NPROP; i += 4) {
    #pragma unroll
    for (int q = 0; q < 4; q++) {
      u64 row = (q == 0) ? p0 : (q == 1) ? p1 : (q == 2) ? p2 : p3;
      int ii = i + q;
      int wi = ii >> 6, ti = ii & 63;
      u32 klo = __shfl((u32)keep, wi);
      u32 khi = __shfl((u32)(keep >> 32), wi);
      u64 kword = (((u64)khi) << 32) | klo;
      if ((kword >> ti) & 1ull) keep &= ~row;
      u64 nxt = LDROW(ii + 4);
      if (q == 0) p0 = nxt; else if (q == 1) p1 = nxt; else if (q == 2) p2 = nxt; else p3 = nxt;
    }
  }

  // phase D2: ordered write of first 300 kept rows via 16-lane prefix scan
  int cntk = (lane < 16) ? __popcll(keep) : 0;
  int inc = cntk;
  #pragma unroll
  for (int off = 1; off < 64; off <<= 1) {
    int v = __shfl_up(inc, off);
    if (lane >= off) inc += v;
  }
  int pre = inc - cntk;
  float imgv = (float)image_ids[b];

  if (lane < 16) {
    int rank = pre;
    u64 kk = keep;
    while (kk) {
      int t = __builtin_ctzll(kk);
      kk &= kk - 1;
      int i = (lane << 6) + t;
      if (rank < MAXOUT) {
        float4 bv = bx[i];
        size_t ro = (size_t)(b * MAXOUT + rank) * 5;
        out[ro + 0] = bv.x;
        out[ro + 1] = bv.y;
        out[ro + 2] = bv.z;
        out[ro + 3] = bv.w;
        out[ro + 4] = scs[i];
        out[BIMG * MAXOUT * 5 + b * MAXOUT + rank] = (float)lbs[i];
        out[BIMG * MAXOUT * 6 + b * MAXOUT + rank] = imgv;
      }
      rank++;
    }
  }
}

extern "C" void kernel_launch(void* const* d_in, const int* in_sizes, int n_in,
                              void* d_out, int out_size, void* d_ws, size_t ws_size,
                              hipStream_t stream) {
  (void)in_sizes; (void)n_in; (void)out_size; (void)ws_size;
  const float* pe = (const float*)d_in[0];
  const float* obj = (const float*)d_in[1];
  const float* boxes = (const float*)d_in[2];
  const float* ce = (const float*)d_in[3];
  const int* image_ids = (const int*)d_in[4];
  float* out = (float*)d_out;

  u64* cand = (u64*)d_ws;   // 8 * 4096 * 8 B = 256 KB total scratch

  hipMemsetAsync(cand, 0, (size_t)BIMG * CSLOT * sizeof(u64), stream);
  score_kernel<<<dim3(1000), dim3(256), 0, stream>>>(pe, obj, ce, cand);
  sort_kernel<<<dim3(BIMG), dim3(1024), 0, stream>>>(cand);
  nms_fused<<<dim3(BIMG), dim3(1024), 0, stream>>>(cand, boxes, image_ids, out);
}

// Round 6
// 542.374 us; speedup vs baseline: 2.9000x; 1.7856x over previous
//
#include <hip/hip_runtime.h>
#include <stdint.h>

typedef unsigned long long u64;
typedef unsigned int u32;

#define BIMG 8
#define NPROP 1000
#define DDIM 512
#define CCLS 1203
#define MAXOUT 300
#define CSLOT 4096      // per-image candidate slots
#define TRIW 8665       // upper-triangle u64 words
#define CTS 1204        // ceT row stride (floats), 16B-aligned rows

__device__ __forceinline__ u32 flipf(float f) {
  u32 u = __float_as_uint(f);
  return (u & 0x80000000u) ? ~u : (u | 0x80000000u);
}
__device__ __forceinline__ float unflipf(u32 x) {
  u32 u = (x & 0x80000000u) ? (x ^ 0x80000000u) : ~x;
  return __uint_as_float(u);
}
__device__ __forceinline__ void push3(float v, float& a0, float& a1, float& a2) {
  if (v > a0) { a2 = a1; a1 = a0; a0 = v; }
  else if (v > a1) { a2 = a1; a1 = v; }
  else if (v > a2) { a2 = v; }
}

// ---------------- stage 0: tiled transpose ce[c][d] -> ceT[d][c] (stride CTS)
__global__ __launch_bounds__(256) void transpose_ce(
    const float* __restrict__ ce, float* __restrict__ ceT)
{
  __shared__ float tile[32][33];
  const int c0 = blockIdx.x * 32, d0 = blockIdx.y * 32;
  const int tx = threadIdx.x, ty = threadIdx.y;   // 32 x 8
  #pragma unroll
  for (int k = 0; k < 4; k++) {
    int c = c0 + ty + k * 8;
    if (c < CCLS) tile[ty + k * 8][tx] = ce[(size_t)c * DDIM + d0 + tx];
  }
  __syncthreads();
  #pragma unroll
  for (int k = 0; k < 4; k++) {
    int d = d0 + ty + k * 8;
    int c = c0 + tx;
    if (c < CCLS) ceT[(size_t)d * CTS + c] = tile[tx][ty + k * 8];
  }
}

// ================= stage 1 (fast path): coalesced ceT loads =================
// thread t owns classes 4t..4t+3 (float4) and 1024+t (t<179, scalar).
__global__ __launch_bounds__(256, 2) void score_kernel_t(
    const float* __restrict__ pe, const float* __restrict__ obj,
    const float* __restrict__ ceT, u64* __restrict__ cand)
{
  __shared__ float pe_s[8][DDIM];      // 16 KB
  __shared__ float red[4][8];
  __shared__ float trip[4][8][3];
  __shared__ u64 rowc[8][16];
  __shared__ u32 rcnt[8];

  const int tid = threadIdx.x;
  const int lane = tid & 63, wv = tid >> 6;
  const int blk = blockIdx.x;
  const int b = blk / 125;
  const int n0 = (blk % 125) * 8;

  {
    const float4* src = (const float4*)(pe + (size_t)(b * NPROP + n0) * DDIM);
    float4* dst = (float4*)&pe_s[0][0];
    for (int i = tid; i < 1024; i += 256) dst[i] = src[i];
  }
  if (tid < 8) rcnt[tid] = 0u;
  __syncthreads();

  // row norms
  float nrm[8];
  #pragma unroll
  for (int r = 0; r < 8; r++) {
    float x0 = pe_s[r][tid], x1 = pe_s[r][tid + 256];
    float s = x0 * x0 + x1 * x1;
    #pragma unroll
    for (int off = 32; off; off >>= 1) s += __shfl_xor(s, off);
    if (lane == 0) red[wv][r] = s;
  }
  __syncthreads();
  #pragma unroll
  for (int r = 0; r < 8; r++)
    nrm[r] = sqrtf(((red[0][r] + red[1][r]) + red[2][r]) + red[3][r]);
  __syncthreads();
  #pragma unroll
  for (int r = 0; r < 8; r++) {
    pe_s[r][tid]       = __fdiv_rn(pe_s[r][tid], nrm[r]);
    pe_s[r][tid + 256] = __fdiv_rn(pe_s[r][tid + 256], nrm[r]);
  }
  __syncthreads();

  const bool v4 = (tid < 179);                 // slot-4 class = 1024+tid
  const int c4c = v4 ? (1024 + tid) : 1202;    // clamped for safe loads

  float acc[5][8];
  #pragma unroll
  for (int k = 0; k < 5; k++)
    #pragma unroll
    for (int r = 0; r < 8; r++) acc[k][r] = 0.f;

  const float4* ps4 = (const float4*)&pe_s[0][0];
  for (int d4 = 0; d4 < 128; d4++) {
    const int d0 = d4 * 4;
    // B: 4 coalesced float4 (classes 4t..4t+3 at d0..d0+3) + 4 scalars (slot 4)
    float4 b0 = *((const float4*)(ceT + (size_t)(d0 + 0) * CTS) + tid);
    float4 b1 = *((const float4*)(ceT + (size_t)(d0 + 1) * CTS) + tid);
    float4 b2 = *((const float4*)(ceT + (size_t)(d0 + 2) * CTS) + tid);
    float4 b3 = *((const float4*)(ceT + (size_t)(d0 + 3) * CTS) + tid);
    float e0 = ceT[(size_t)(d0 + 0) * CTS + c4c];
    float e1 = ceT[(size_t)(d0 + 1) * CTS + c4c];
    float e2 = ceT[(size_t)(d0 + 2) * CTS + c4c];
    float e3 = ceT[(size_t)(d0 + 3) * CTS + c4c];
    #pragma unroll
    for (int r = 0; r < 8; r++) {
      float4 a = ps4[r * 128 + d4];   // pe row r, dims d0..d0+3 (LDS broadcast)
      // slot 0 (class 4t):   d-sequential fmaf chain (bitwise same order as R5)
      acc[0][r] = fmaf(a.x, b0.x, acc[0][r]); acc[0][r] = fmaf(a.y, b1.x, acc[0][r]);
      acc[0][r] = fmaf(a.z, b2.x, acc[0][r]); acc[0][r] = fmaf(a.w, b3.x, acc[0][r]);
      acc[1][r] = fmaf(a.x, b0.y, acc[1][r]); acc[1][r] = fmaf(a.y, b1.y, acc[1][r]);
      acc[1][r] = fmaf(a.z, b2.y, acc[1][r]); acc[1][r] = fmaf(a.w, b3.y, acc[1][r]);
      acc[2][r] = fmaf(a.x, b0.z, acc[2][r]); acc[2][r] = fmaf(a.y, b1.z, acc[2][r]);
      acc[2][r] = fmaf(a.z, b2.z, acc[2][r]); acc[2][r] = fmaf(a.w, b3.z, acc[2][r]);
      acc[3][r] = fmaf(a.x, b0.w, acc[3][r]); acc[3][r] = fmaf(a.y, b1.w, acc[3][r]);
      acc[3][r] = fmaf(a.z, b2.w, acc[3][r]); acc[3][r] = fmaf(a.w, b3.w, acc[3][r]);
      acc[4][r] = fmaf(a.x, e0, acc[4][r]);   acc[4][r] = fmaf(a.y, e1, acc[4][r]);
      acc[4][r] = fmaf(a.z, e2, acc[4][r]);   acc[4][r] = fmaf(a.w, e3, acc[4][r]);
    }
  }

  #pragma unroll
  for (int k = 0; k < 5; k++)
    #pragma unroll
    for (int r = 0; r < 8; r++) acc[k][r] = __fdiv_rn(acc[k][r], 0.01f);
  if (!v4) {
    #pragma unroll
    for (int r = 0; r < 8; r++) acc[4][r] = -INFINITY;
  }

  // per-row top-3 of logits
  float t0[8], t1[8], t2[8];
  #pragma unroll
  for (int r = 0; r < 8; r++) {
    t0[r] = t1[r] = t2[r] = -INFINITY;
    push3(acc[0][r], t0[r], t1[r], t2[r]);
    push3(acc[1][r], t0[r], t1[r], t2[r]);
    push3(acc[2][r], t0[r], t1[r], t2[r]);
    push3(acc[3][r], t0[r], t1[r], t2[r]);
    push3(acc[4][r], t0[r], t1[r], t2[r]);
  }
  #pragma unroll
  for (int off = 32; off; off >>= 1) {
    #pragma unroll
    for (int r = 0; r < 8; r++) {
      float u0 = __shfl_xor(t0[r], off);
      float u1 = __shfl_xor(t1[r], off);
      float u2 = __shfl_xor(t2[r], off);
      push3(u0, t0[r], t1[r], t2[r]);
      push3(u1, t0[r], t1[r], t2[r]);
      push3(u2, t0[r], t1[r], t2[r]);
    }
  }
  if (lane == 0) {
    #pragma unroll
    for (int r = 0; r < 8; r++) {
      trip[wv][r][0] = t0[r]; trip[wv][r][1] = t1[r]; trip[wv][r][2] = t2[r];
    }
  }
  __syncthreads();
  float m[8], s3[8];
  #pragma unroll
  for (int r = 0; r < 8; r++) {
    float a0 = -INFINITY, a1 = -INFINITY, a2 = -INFINITY;
    #pragma unroll
    for (int w = 0; w < 4; w++) {
      push3(trip[w][r][0], a0, a1, a2);
      push3(trip[w][r][1], a0, a1, a2);
      push3(trip[w][r][2], a0, a1, a2);
    }
    m[r] = a0; s3[r] = a2;
  }

  // softmax denominator
  float sm[8];
  #pragma unroll
  for (int r = 0; r < 8; r++) {
    float ls = expf(acc[0][r] - m[r]);
    ls += expf(acc[1][r] - m[r]);
    ls += expf(acc[2][r] - m[r]);
    ls += expf(acc[3][r] - m[r]);
    ls += expf(acc[4][r] - m[r]);
    #pragma unroll
    for (int off = 32; off; off >>= 1) ls += __shfl_xor(ls, off);
    if (lane == 0) red[wv][r] = ls;
  }
  __syncthreads();
  #pragma unroll
  for (int r = 0; r < 8; r++)
    sm[r] = ((red[0][r] + red[1][r]) + red[2][r]) + red[3][r];

  float v3[8], objv[8];
  #pragma unroll
  for (int r = 0; r < 8; r++) {
    v3[r] = __fdiv_rn(expf(s3[r] - m[r]), sm[r]);
    objv[r] = obj[b * NPROP + n0 + r];
  }

  // emit: p >= v3 && p > 0 && score > 0.01
  #pragma unroll
  for (int k = 0; k < 5; k++) {
    if (k == 4 && !v4) continue;
    const int c = (k < 4) ? (4 * tid + k) : (1024 + tid);
    #pragma unroll
    for (int r = 0; r < 8; r++) {
      float e = expf(acc[k][r] - m[r]);
      float p = __fdiv_rn(e, sm[r]);
      if (p >= v3[r] && p > 0.f) {
        float sc = __fadd_rn(__fmul_rn(p, 0.65f), __fmul_rn(objv[r], 0.35f));
        if (sc > 0.01f) {
          u32 flat = (u32)(n0 + r) * (u32)CCLS + (u32)c;
          u64 key = (((u64)flipf(sc)) << 32) | (u32)(~flat);
          u32 slot = atomicAdd(&rcnt[r], 1u);
          if (slot < 16u) rowc[r][slot] = key;
        }
      }
    }
  }
  __syncthreads();
  if (tid < 8) {
    int n = (int)rcnt[tid]; if (n > 16) n = 16;
    for (int a2 = 1; a2 < n; a2++) {
      u64 kx = rowc[tid][a2]; int bp = a2 - 1;
      while (bp >= 0 && rowc[tid][bp] < kx) { rowc[tid][bp + 1] = rowc[tid][bp]; bp--; }
      rowc[tid][bp + 1] = kx;
    }
    int mth = n < 4 ? n : 4;
    u64* dst = cand + (size_t)b * CSLOT + (size_t)(n0 + tid) * 4;
    for (int s2 = 0; s2 < mth; s2++) dst[s2] = rowc[tid][s2];
  }
}

// ================= stage 1 (fallback): original gather version =================
__global__ __launch_bounds__(256, 2) void score_kernel(
    const float* __restrict__ pe, const float* __restrict__ obj,
    const float* __restrict__ ce, u64* __restrict__ cand)
{
  __shared__ float pe_s[8][DDIM];
  __shared__ float red[4][8];
  __shared__ float trip[4][8][3];
  __shared__ u64 rowc[8][16];
  __shared__ u32 rcnt[8];

  const int tid = threadIdx.x;
  const int lane = tid & 63, wv = tid >> 6;
  const int blk = blockIdx.x;
  const int b = blk / 125;
  const int n0 = (blk % 125) * 8;

  {
    const float4* src = (const float4*)(pe + (size_t)(b * NPROP + n0) * DDIM);
    float4* dst = (float4*)&pe_s[0][0];
    for (int i = tid; i < 1024; i += 256) dst[i] = src[i];
  }
  if (tid < 8) rcnt[tid] = 0u;
  __syncthreads();

  float nrm[8];
  #pragma unroll
  for (int r = 0; r < 8; r++) {
    float x0 = pe_s[r][tid], x1 = pe_s[r][tid + 256];
    float s = x0 * x0 + x1 * x1;
    #pragma unroll
    for (int off = 32; off; off >>= 1) s += __shfl_xor(s, off);
    if (lane == 0) red[wv][r] = s;
  }
  __syncthreads();
  #pragma unroll
  for (int r = 0; r < 8; r++)
    nrm[r] = sqrtf(((red[0][r] + red[1][r]) + red[2][r]) + red[3][r]);
  __syncthreads();
  #pragma unroll
  for (int r = 0; r < 8; r++) {
    pe_s[r][tid]       = __fdiv_rn(pe_s[r][tid], nrm[r]);
    pe_s[r][tid + 256] = __fdiv_rn(pe_s[r][tid + 256], nrm[r]);
  }
  __syncthreads();

  const int c4 = 1024 + tid;
  const bool v4 = (c4 < CCLS);
  const float4* ceb = (const float4*)ce;
  const float4* pc0 = ceb + (size_t)(tid)       * 128;
  const float4* pc1 = ceb + (size_t)(tid + 256) * 128;
  const float4* pc2 = ceb + (size_t)(tid + 512) * 128;
  const float4* pc3 = ceb + (size_t)(tid + 768) * 128;
  const float4* pc4 = ceb + (size_t)(v4 ? c4 : (CCLS - 1)) * 128;

  float acc[5][8];
  #pragma unroll
  for (int k = 0; k < 5; k++)
    #pragma unroll
    for (int r = 0; r < 8; r++) acc[k][r] = 0.f;

  const float4* ps4 = (const float4*)&pe_s[0][0];
  for (int d4 = 0; d4 < 128; d4++) {
    float4 bv0 = pc0[d4], bv1 = pc1[d4], bv2 = pc2[d4], bv3 = pc3[d4], bv4 = pc4[d4];
    #pragma unroll
    for (int r = 0; r < 8; r++) {
      float4 a = ps4[r * 128 + d4];
      acc[0][r] = fmaf(a.x, bv0.x, acc[0][r]); acc[0][r] = fmaf(a.y, bv0.y, acc[0][r]);
      acc[0][r] = fmaf(a.z, bv0.z, acc[0][r]); acc[0][r] = fmaf(a.w, bv0.w, acc[0][r]);
      acc[1][r] = fmaf(a.x, bv1.x, acc[1][r]); acc[1][r] = fmaf(a.y, bv1.y, acc[1][r]);
      acc[1][r] = fmaf(a.z, bv1.z, acc[1][r]); acc[1][r] = fmaf(a.w, bv1.w, acc[1][r]);
      acc[2][r] = fmaf(a.x, bv2.x, acc[2][r]); acc[2][r] = fmaf(a.y, bv2.y, acc[2][r]);
      acc[2][r] = fmaf(a.z, bv2.z, acc[2][r]); acc[2][r] = fmaf(a.w, bv2.w, acc[2][r]);
      acc[3][r] = fmaf(a.x, bv3.x, acc[3][r]); acc[3][r] = fmaf(a.y, bv3.y, acc[3][r]);
      acc[3][r] = fmaf(a.z, bv3.z, acc[3][r]); acc[3][r] = fmaf(a.w, bv3.w, acc[3][r]);
      acc[4][r] = fmaf(a.x, bv4.x, acc[4][r]); acc[4][r] = fmaf(a.y, bv4.y, acc[4][r]);
      acc[4][r] = fmaf(a.z, bv4.z, acc[4][r]); acc[4][r] = fmaf(a.w, bv4.w, acc[4][r]);
    }
  }

  #pragma unroll
  for (int k = 0; k < 5; k++)
    #pragma unroll
    for (int r = 0; r < 8; r++) acc[k][r] = __fdiv_rn(acc[k][r], 0.01f);
  if (!v4) {
    #pragma unroll
    for (int r = 0; r < 8; r++) acc[4][r] = -INFINITY;
  }

  float t0[8], t1[8], t2[8];
  #pragma unroll
  for (int r = 0; r < 8; r++) {
    t0[r] = t1[r] = t2[r] = -INFINITY;
    push3(acc[0][r], t0[r], t1[r], t2[r]);
    push3(acc[1][r], t0[r], t1[r], t2[r]);
    push3(acc[2][r], t0[r], t1[r], t2[r]);
    push3(acc[3][r], t0[r], t1[r], t2[r]);
    push3(acc[4][r], t0[r], t1[r], t2[r]);
  }
  #pragma unroll
  for (int off = 32; off; off >>= 1) {
    #pragma unroll
    for (int r = 0; r < 8; r++) {
      float u0 = __shfl_xor(t0[r], off);
      float u1 = __shfl_xor(t1[r], off);
      float u2 = __shfl_xor(t2[r], off);
      push3(u0, t0[r], t1[r], t2[r]);
      push3(u1, t0[r], t1[r], t2[r]);
      push3(u2, t0[r], t1[r], t2[r]);
    }
  }
  if (lane == 0) {
    #pragma unroll
    for (int r = 0; r < 8; r++) {
      trip[wv][r][0] = t0[r]; trip[wv][r][1] = t1[r]; trip[wv][r][2] = t2[r];
    }
  }
  __syncthreads();
  float m[8], s3[8];
  #pragma unroll
  for (int r = 0; r < 8; r++) {
    float a0 = -INFINITY, a1 = -INFINITY, a2 = -INFINITY;
    #pragma unroll
    for (int w = 0; w < 4; w++) {
      push3(trip[w][r][0], a0, a1, a2);
      push3(trip[w][r][1], a0, a1, a2);
      push3(trip[w][r][2], a0, a1, a2);
    }
    m[r] = a0; s3[r] = a2;
  }

  float sm[8];
  #pragma unroll
  for (int r = 0; r < 8; r++) {
    float ls = expf(acc[0][r] - m[r]);
    ls += expf(acc[1][r] - m[r]);
    ls += expf(acc[2][r] - m[r]);
    ls += expf(acc[3][r] - m[r]);
    ls += expf(acc[4][r] - m[r]);
    #pragma unroll
    for (int off = 32; off; off >>= 1) ls += __shfl_xor(ls, off);
    if (lane == 0) red[wv][r] = ls;
  }
  __syncthreads();
  #pragma unroll
  for (int r = 0; r < 8; r++)
    sm[r] = ((red[0][r] + red[1][r]) + red[2][r]) + red[3][r];

  float v3[8], objv[8];
  #pragma unroll
  for (int r = 0; r < 8; r++) {
    v3[r] = __fdiv_rn(expf(s3[r] - m[r]), sm[r]);
    objv[r] = obj[b * NPROP + n0 + r];
  }

  #pragma unroll
  for (int k = 0; k < 5; k++) {
    if (k == 4 && !v4) continue;
    const int c = tid + (k << 8);
    #pragma unroll
    for (int r = 0; r < 8; r++) {
      float e = expf(acc[k][r] - m[r]);
      float p = __fdiv_rn(e, sm[r]);
      if (p >= v3[r] && p > 0.f) {
        float sc = __fadd_rn(__fmul_rn(p, 0.65f), __fmul_rn(objv[r], 0.35f));
        if (sc > 0.01f) {
          u32 flat = (u32)(n0 + r) * (u32)CCLS + (u32)c;
          u64 key = (((u64)flipf(sc)) << 32) | (u32)(~flat);
          u32 slot = atomicAdd(&rcnt[r], 1u);
          if (slot < 16u) rowc[r][slot] = key;
        }
      }
    }
  }
  __syncthreads();
  if (tid < 8) {
    int n = (int)rcnt[tid]; if (n > 16) n = 16;
    for (int a2 = 1; a2 < n; a2++) {
      u64 kx = rowc[tid][a2]; int bp = a2 - 1;
      while (bp >= 0 && rowc[tid][bp] < kx) { rowc[tid][bp + 1] = rowc[tid][bp]; bp--; }
      rowc[tid][bp + 1] = kx;
    }
    int mth = n < 4 ? n : 4;
    u64* dst = cand + (size_t)b * CSLOT + (size_t)(n0 + tid) * 4;
    for (int s2 = 0; s2 < mth; s2++) dst[s2] = rowc[tid][s2];
  }
}

// ---------------- stage 2: per-image in-place bitonic sort of 4096 keys (desc)
__global__ __launch_bounds__(1024) void sort_kernel(u64* __restrict__ cand)
{
  __shared__ u64 s[CSLOT];
  const int tid = threadIdx.x;
  u64* cb = cand + (size_t)blockIdx.x * CSLOT;
  for (int i = tid; i < CSLOT; i += 1024) s[i] = cb[i];
  __syncthreads();
  for (int k = 2; k <= CSLOT; k <<= 1) {
    for (int j = k >> 1; j > 0; j >>= 1) {
      for (int i = tid; i < CSLOT; i += 1024) {
        int ixj = i ^ j;
        if (ixj > i) {
          u64 a = s[i], c = s[ixj];
          if (((i & k) == 0) ? (a < c) : (a > c)) { s[i] = c; s[ixj] = a; }
        }
      }
      __syncthreads();
    }
  }
  for (int i = tid; i < CSLOT; i += 1024) cb[i] = s[i];
}

// ---------------- stage 3: fused decode + triangle IoU + wave-parallel NMS + f32 out
__global__ __launch_bounds__(1024) void nms_fused(
    const u64* __restrict__ cand, const float* __restrict__ boxes,
    const int* __restrict__ image_ids, float* __restrict__ out)
{
  __shared__ u64 supw[TRIW];
  __shared__ float4 bx[NPROP];
  __shared__ float ar[NPROP];
  __shared__ float scs[NPROP];
  __shared__ int lbs[NPROP];

  const int tid = threadIdx.x;
  const int b = blockIdx.x;

  for (int i = tid; i < NPROP; i += 1024) {
    u64 key = cand[(size_t)b * CSLOT + i];
    float sc = -1.0f; int pid = 0, lab = -1;
    if (key != 0ull) {
      sc = unflipf((u32)(key >> 32));
      u32 flat = ~(u32)key;
      pid = (int)(flat / (u32)CCLS);
      lab = (int)(flat % (u32)CCLS);
    }
    float4 v = ((const float4*)boxes)[b * NPROP + pid];
    bx[i] = v;
    ar[i] = __fmul_rn(fmaxf(__fsub_rn(v.z, v.x), 0.f),
                      fmaxf(__fsub_rn(v.w, v.y), 0.f));
    scs[i] = sc;
    lbs[i] = lab;
  }
  __syncthreads();

  for (int i = tid; i < NPROP; i += 1024) {
    float4 bi = bx[i]; float ai = ar[i]; int li = lbs[i];
    int g = i >> 6, t = i - (g << 6);
    int rb = 16 * i - (32 * g * (g - 1) + g * (t + 1));
    int w0 = (i + 1) >> 6;
    for (int w = w0; w < 16; w++) {
      u64 bits = 0;
      int jb = w << 6;
      int ts = (w == g) ? (t + 1) : 0;
      int te = NPROP - jb; if (te > 64) te = 64;
      for (int tt = ts; tt < te; tt++) {
        int j = jb + tt;
        if (lbs[j] != li) continue;
        float4 bj = bx[j];
        float iw = fmaxf(__fsub_rn(fminf(bi.z, bj.z), fmaxf(bi.x, bj.x)), 0.f);
        float ih = fmaxf(__fsub_rn(fminf(bi.w, bj.w), fmaxf(bi.y, bj.y)), 0.f);
        float inter = __fmul_rn(iw, ih);
        if (inter <= 0.f) continue;
        float uni = __fsub_rn(__fadd_rn(ai, ar[j]), inter);
        if (__fdiv_rn(inter, fmaxf(uni, 1e-6f)) > 0.5f) bits |= (1ull << tt);
      }
      supw[rb + w - w0] = bits;
    }
  }
  __syncthreads();

  for (int j = tid; j < MAXOUT * 5; j += 1024)
    out[(size_t)b * MAXOUT * 5 + j] = 0.f;
  for (int j = tid; j < MAXOUT; j += 1024) {
    out[BIMG * MAXOUT * 5 + b * MAXOUT + j] = -1.f;
    out[BIMG * MAXOUT * 6 + b * MAXOUT + j] = -1.f;
  }
  __syncthreads();

  if (tid >= 64) return;
  const int lane = tid, myw = lane & 15;

  u64 keep = 0;
  if (lane < 16) {
    #pragma unroll 4
    for (int t = 0; t < 64; t++) {
      int i = (lane << 6) + t;
      if (i < NPROP && scs[i] > 0.01f) keep |= (1ull << t);
    }
  }

  auto LDROW = [&](int i) -> u64 {
    if (i >= NPROP || lane >= 16) return 0ull;
    int g = i >> 6, t = i & 63;
    int w0 = (i + 1) >> 6;
    if (myw < w0) return 0ull;
    int rb = 16 * i - (32 * g * (g - 1) + g * (t + 1));
    return supw[rb + myw - w0];
  };

  u64 p0 = LDROW(0), p1 = LDROW(1), p2 = LDROW(2), p3 = LDROW(3);
  for (int i = 0; i < NPROP; i += 4) {
    #pragma unroll
    for (int q = 0; q < 4; q++) {
      u64 row = (q == 0) ? p0 : (q == 1) ? p1 : (q == 2) ? p2 : p3;
      int ii = i + q;
      int wi = ii >> 6, ti = ii & 63;
      u32 klo = __shfl((u32)keep, wi);
      u32 khi = __shfl((u32)(keep >> 32), wi);
      u64 kword = (((u64)khi) << 32) | klo;
      if ((kword >> ti) & 1ull) keep &= ~row;
      u64 nxt = LDROW(ii + 4);
      if (q == 0) p0 = nxt; else if (q == 1) p1 = nxt; else if (q == 2) p2 = nxt; else p3 = nxt;
    }
  }

  int cntk = (lane < 16) ? __popcll(keep) : 0;
  int inc = cntk;
  #pragma unroll
  for (int off = 1; off < 64; off <<= 1) {
    int v = __shfl_up(inc, off);
    if (lane >= off) inc += v;
  }
  int pre = inc - cntk;
  float imgv = (float)image_ids[b];

  if (lane < 16) {
    int rank = pre;
    u64 kk = keep;
    while (kk) {
      int t = __builtin_ctzll(kk);
      kk &= kk - 1;
      int i = (lane << 6) + t;
      if (rank < MAXOUT) {
        float4 bv = bx[i];
        size_t ro = (size_t)(b * MAXOUT + rank) * 5;
        out[ro + 0] = bv.x;
        out[ro + 1] = bv.y;
        out[ro + 2] = bv.z;
        out[ro + 3] = bv.w;
        out[ro + 4] = scs[i];
        out[BIMG * MAXOUT * 5 + b * MAXOUT + rank] = (float)lbs[i];
        out[BIMG * MAXOUT * 6 + b * MAXOUT + rank] = imgv;
      }
      rank++;
    }
  }
}

extern "C" void kernel_launch(void* const* d_in, const int* in_sizes, int n_in,
                              void* d_out, int out_size, void* d_ws, size_t ws_size,
                              hipStream_t stream) {
  (void)in_sizes; (void)n_in; (void)out_size;
  const float* pe = (const float*)d_in[0];
  const float* obj = (const float*)d_in[1];
  const float* boxes = (const float*)d_in[2];
  const float* ce = (const float*)d_in[3];
  const int* image_ids = (const int*)d_in[4];
  float* out = (float*)d_out;

  const size_t candB = (size_t)BIMG * CSLOT * sizeof(u64);       // 256 KB
  const size_t ceTB  = (size_t)DDIM * CTS * sizeof(float);       // ~2.47 MB
  u64* cand = (u64*)d_ws;
  float* ceT = (float*)((char*)d_ws + candB);

  hipMemsetAsync(cand, 0, candB, stream);
  if (ws_size >= candB + ceTB) {
    transpose_ce<<<dim3(38, 16), dim3(32, 8), 0, stream>>>(ce, ceT);
    score_kernel_t<<<dim3(1000), dim3(256), 0, stream>>>(pe, obj, ceT, cand);
  } else {
    score_kernel<<<dim3(1000), dim3(256), 0, stream>>>(pe, obj, ce, cand);
  }
  sort_kernel<<<dim3(BIMG), dim3(1024), 0, stream>>>(cand);
  nms_fused<<<dim3(BIMG), dim3(1024), 0, stream>>>(cand, boxes, image_ids, out);
}